// Round 13
// baseline (630.821 us; speedup 1.0000x reference)
//
#include <hip/hip_runtime.h>
#include <math.h>

#define BB 8
#define NN 2048
#define NPOINT 102
#define H_REP 0.0005f

typedef float v2f __attribute__((ext_vector_type(2)));

__device__ const int    c_ns[5]   = {8, 12, 16, 20, 24};
__device__ const double c_p[5]    = {0.004, 0.006, 0.008, 0.01, 0.012};
__device__ const int    c_goff[5] = {0, 6528, 16320, 29376, 45696};  // ints; 816*ns prefix
__device__ const int    c_nblk[5] = {7, 10, 13, 16, 20};             // ceil(M/128)
__device__ const int    c_npre[6] = {0, 7, 17, 30, 46, 66};          // prefix of nblk

// part layout (doubles): cdpart[512] | reppart[256] | ukpart[1600]
#define OFF_CD 0
#define OFF_REP 512
#define OFF_UK 768
// flags (ints): fpsdone[8] | ballcnt[40] | done | ukdone
#define F_FPS 0
#define F_BALL 8
#define F_DONE 48
#define F_UKD 49
#define N_FLAGS 50
#define DONE_TARGET 776  // 256 cd + 256 rep + 264 uknn

__device__ inline int aload(const int* p) {
    return __hip_atomic_load(p, __ATOMIC_ACQUIRE, __HIP_MEMORY_SCOPE_AGENT);
}
__device__ inline void astore(int* p, int v) {
    __hip_atomic_store(p, v, __ATOMIC_RELEASE, __HIP_MEMORY_SCOPE_AGENT);
}
__device__ inline void astore_d(double* p, double v) {
    __hip_atomic_store(p, v, __ATOMIC_RELAXED, __HIP_MEMORY_SCOPE_AGENT);
}
__device__ inline double aload_d(const double* p) {
    return __hip_atomic_load(p, __ATOMIC_RELAXED, __HIP_MEMORY_SCOPE_AGENT);
}

// branchless sorted-5 insert (keeps t0<=t1<=t2<=t3<=t4)
__device__ inline void ins5(float c, float& t0, float& t1, float& t2, float& t3, float& t4) {
    float lo;
    lo = fminf(t0, c); c = fmaxf(t0, c); t0 = lo;
    lo = fminf(t1, c); c = fmaxf(t1, c); t1 = lo;
    lo = fminf(t2, c); c = fmaxf(t2, c); t2 = lo;
    lo = fminf(t3, c); c = fmaxf(t3, c); t3 = lo;
    t4 = fminf(t4, c);
}

union SMem {
    struct { float4 sB[NN]; float pm[4][128]; } cd;                      // 34 KB
    struct { float4 sP[NN]; float pm[4][64][5]; } rep;                   // 37.9 KB
    struct { float4 sP[NN]; float2 sl[2][4]; int sFi[NPOINT]; } fps;     // 32.5 KB
    struct { v2f sX[1224], sY[1224], sZ[1224]; float pm1[4][128], pm2[4][128]; } uk;  // 33.4 KB
};

// ---- ball scan for one (pi,b,c) task; all lanes of one wave ----
__device__ inline void ball_task(const float* __restrict__ pred,
                                 const int* __restrict__ fidx,
                                 int* __restrict__ gidx,
                                 int* __restrict__ flags,
                                 int t, int lane) {
    int pi = t / 816;
    int rem = t - pi * 816;
    int b = rem / NPOINT;
    int c = rem - b * NPOINT;
    // wait for this batch's FPS
    while (aload(&flags[F_FPS + b]) == 0) __builtin_amdgcn_s_sleep(2);
    int ns = c_ns[pi];
    double rd = sqrt(c_p[pi]);
    float r2 = (float)(rd * rd);
    const float* pp = pred + (size_t)b * NN * 3;
    int ci = aload(&fidx[b * NPOINT + c]);
    float cx = pp[ci * 3 + 0], cy = pp[ci * 3 + 1], cz = pp[ci * 3 + 2];
    float sc = cx * cx + cy * cy + cz * cz;
    int* outp = gidx + c_goff[pi] + ((size_t)b * NPOINT + c) * ns;
    int cnt = 0;
    int first = 0;
    for (int j0 = 0; j0 < NN && cnt < ns; j0 += 64) {
        int j = j0 + lane;
        float x = pp[j * 3 + 0], y = pp[j * 3 + 1], z = pp[j * 3 + 2];
        float sj = x * x + y * y + z * z;
        float d2 = fmaxf(sc + sj - 2.0f * (cx * x + cy * y + cz * z), 0.0f);
        bool prd = d2 < r2;
        unsigned long long mask = __ballot(prd);
        if (cnt == 0 && mask != 0ull) first = j0 + (int)__builtin_ctzll(mask);
        if (prd) {
            int pos = cnt + (int)__popcll(mask & ((1ull << lane) - 1ull));
            if (pos < ns) __hip_atomic_store(&outp[pos], j, __ATOMIC_RELAXED,
                                             __HIP_MEMORY_SCOPE_AGENT);
        }
        cnt += (int)__popcll(mask);
    }
    if (cnt < ns) {
        for (int s = cnt + lane; s < ns; s += 64)
            __hip_atomic_store(&outp[s], first, __ATOMIC_RELAXED, __HIP_MEMORY_SCOPE_AGENT);
    }
    __threadfence();
    if (lane == 0) atomicAdd(&flags[F_BALL + pi * 8 + b], 1);
}

// ================= ONE kernel, flag-chained phases, no grid.sync =================
__global__ __launch_bounds__(256, 4) void k_mega(const float* __restrict__ pred,
                                                 const float* __restrict__ gt,
                                                 const float* __restrict__ radius,
                                                 int* __restrict__ fidx,
                                                 int* __restrict__ gidx,
                                                 double* __restrict__ part,
                                                 int* __restrict__ flags,
                                                 float* __restrict__ out) {
    __shared__ SMem sm;
    __shared__ int sLast;
    int bid = blockIdx.x;
    int tid = threadIdx.x;
    int lane = tid & 63, wid = tid >> 6;

    if (bid < 8) {
        // ========== FPS: 4 waves x 8 pts/lane, DPP argmax, fidx buffered in LDS ==========
        __builtin_amdgcn_s_setprio(1);
        int b = bid;
        const float* pp = pred + (size_t)b * NN * 3;
        float px[8], py[8], pz[8], dist[8];
#pragma unroll
        for (int k = 0; k < 8; k++) {
            int i = (wid << 9) + (k << 6) + lane;  // wave wid owns [wid*512, wid*512+512)
            float x = pp[i * 3 + 0], y = pp[i * 3 + 1], z = pp[i * 3 + 2];
            px[k] = x; py[k] = y; pz[k] = z; dist[k] = 1e10f;
            sm.fps.sP[i] = make_float4(x, y, z, 0.0f);
        }
        if (tid == 0) sm.fps.sFi[0] = 0;
        __syncthreads();
        int last = 0;
#pragma unroll 1
        for (int step = 1; step < NPOINT; ++step) {
            float4 lp = sm.fps.sP[last];
            float bv = -1.0f;
            int bi = 0;
#pragma unroll
            for (int k = 0; k < 8; k++) {
                float dx = px[k] - lp.x, dy = py[k] - lp.y, dz = pz[k] - lp.z;
                float nd = fminf(dist[k], dx * dx + dy * dy + dz * dz);
                dist[k] = nd;
                bool better = nd > bv;  // ascending k -> first-max kept (min global idx)
                bv = better ? nd : bv;
                bi = better ? ((wid << 9) + (k << 6) + lane) : bi;
            }
            // wave-64 argmax: row_ror 1,2,4,8 + bcast15/31 (idempotent -> bcast-safe)
            {
                float v2; int i2; bool take;
#define DPPC(CTRL)                                                                          \
                v2 = __int_as_float(__builtin_amdgcn_update_dpp(                            \
                        __float_as_int(bv), __float_as_int(bv), CTRL, 0xF, 0xF, false));    \
                i2 = __builtin_amdgcn_update_dpp(bi, bi, CTRL, 0xF, 0xF, false);            \
                take = (v2 > bv) || (v2 == bv && i2 < bi);                                  \
                bv = take ? v2 : bv; bi = take ? i2 : bi;
                DPPC(0x121)
                DPPC(0x122)
                DPPC(0x124)
                DPPC(0x128)
                DPPC(0x142)
                DPPC(0x143)
#undef DPPC
            }
            int pb = step & 1;
            if (lane == 63) sm.fps.sl[pb][wid] = make_float2(bv, __int_as_float(bi));
            __syncthreads();  // no pending vmem in loop -> lgkm-only drain
            float fv = -2.0f;
            int fi = 0;
#pragma unroll
            for (int w = 0; w < 4; w++) {  // ascending wave -> disjoint ascending idx ranges
                float2 s = sm.fps.sl[pb][w];
                int i2 = __float_as_int(s.y);
                bool take = (s.x > fv) || (s.x == fv && i2 < fi);
                fv = take ? s.x : fv;
                fi = take ? i2 : fi;
            }
            if (tid == 0) sm.fps.sFi[step] = fi;
            last = fi;  // uniform; double-buffered slots -> no second barrier
        }
        __syncthreads();
        for (int s = tid; s < NPOINT; s += 256) {
            __hip_atomic_store(&fidx[b * NPOINT + s], sm.fps.sFi[s], __ATOMIC_RELAXED,
                               __HIP_MEMORY_SCOPE_AGENT);
        }
        __threadfence();
        __syncthreads();
        if (tid == 0) astore(&flags[F_FPS + b], 1);
    } else if (bid < 264) {
        // ========== chamfer: 2 rows/lane (128 rows/block), 4 waves x 512-pt chunks ==========
        int r = bid - 8;
        int z = r >> 7;
        int b = (r >> 4) & 7;
        int xb = r & 15;
        const float* A = z ? pred : gt;
        const float* Bp = z ? gt : pred;
        const float* bb = Bp + (size_t)b * NN * 3;
        for (int j = tid; j < NN; j += 256) {
            sm.cd.sB[j] = make_float4(bb[j * 3 + 0], bb[j * 3 + 1], bb[j * 3 + 2], 0.0f);
        }
        int rowA = xb * 128 + lane;
        int rowB = rowA + 64;
        const float* aA = A + ((size_t)b * NN + rowA) * 3;
        const float* aB = A + ((size_t)b * NN + rowB) * 3;
        float axA = aA[0], ayA = aA[1], azA = aA[2];
        float axB = aB[0], ayB = aB[1], azB = aB[2];
        __syncthreads();
        float mnA = 1e30f, mnB = 1e30f;
        int j0 = wid * 512;
#pragma unroll 8
        for (int jj = 0; jj < 512; jj++) {
            float4 p = sm.cd.sB[j0 + jj];
            float dxA = axA - p.x, dyA = ayA - p.y, dzA = azA - p.z;
            mnA = fminf(mnA, dxA * dxA + dyA * dyA + dzA * dzA);
            float dxB = axB - p.x, dyB = ayB - p.y, dzB = azB - p.z;
            mnB = fminf(mnB, dxB * dxB + dyB * dyB + dzB * dzB);
        }
        sm.cd.pm[wid][lane] = mnA;
        sm.cd.pm[wid][64 + lane] = mnB;
        __syncthreads();
        if (tid < 128) {
            double v = (double)fminf(fminf(sm.cd.pm[0][tid], sm.cd.pm[1][tid]),
                                     fminf(sm.cd.pm[2][tid], sm.cd.pm[3][tid]));
            for (int off = 32; off; off >>= 1) v += __shfl_down(v, off, 64);
            if (lane == 0) astore_d(&part[OFF_CD + r * 2 + (tid >> 6)], v);
        }
        __syncthreads();
        if (tid == 0) atomicAdd(&flags[F_DONE], 1);
    } else if (bid < 520) {
        // ========== repulsion: 4 waves x 512-pt chunks, 64 rows/block ==========
        int r = bid - 264;
        int b = r >> 5;
        int xb = r & 31;
        const float* pp = pred + (size_t)b * NN * 3;
        for (int j = tid; j < NN; j += 256) {
            sm.rep.sP[j] = make_float4(pp[j * 3 + 0], pp[j * 3 + 1], pp[j * 3 + 2], 0.0f);
        }
        int row = xb * 64 + lane;
        __syncthreads();
        float4 q = sm.rep.sP[row];
        float t0 = 1e30f, t1 = 1e30f, t2 = 1e30f, t3 = 1e30f, t4 = 1e30f;
        int j0 = wid * 512;
#pragma unroll 8
        for (int jj = 0; jj < 512; jj++) {
            float4 p = sm.rep.sP[j0 + jj];
            float dx = q.x - p.x, dy = q.y - p.y, dz = q.z - p.z;
            ins5(dx * dx + dy * dy + dz * dz, t0, t1, t2, t3, t4);
        }
        sm.rep.pm[wid][lane][0] = t0; sm.rep.pm[wid][lane][1] = t1;
        sm.rep.pm[wid][lane][2] = t2; sm.rep.pm[wid][lane][3] = t3;
        sm.rep.pm[wid][lane][4] = t4;
        __syncthreads();
        if (tid < 64) {
            t0 = sm.rep.pm[0][lane][0]; t1 = sm.rep.pm[0][lane][1]; t2 = sm.rep.pm[0][lane][2];
            t3 = sm.rep.pm[0][lane][3]; t4 = sm.rep.pm[0][lane][4];
#pragma unroll
            for (int w = 1; w < 4; w++) {
#pragma unroll
                for (int k = 0; k < 5; k++) ins5(sm.rep.pm[w][lane][k], t0, t1, t2, t3, t4);
            }
            float s = fmaxf(H_REP - t1, 0.f) + fmaxf(H_REP - t2, 0.f) +
                      fmaxf(H_REP - t3, 0.f) + fmaxf(H_REP - t4, 0.f);
            double v = (double)s;
            for (int off = 32; off; off >>= 1) v += __shfl_down(v, off, 64);
            if (tid == 0) astore_d(&part[OFF_REP + r], v);
        }
        __syncthreads();
        if (tid == 0) atomicAdd(&flags[F_DONE], 1);
    }

    if (bid < 520) {
        // ---------------- ball phase: 4080 wave-tasks over blocks [0,520) ----------------
        int g = bid * 4 + wid;
        for (int t = g; t < 4080; t += 2080) ball_task(pred, fidx, gidx, flags, t, lane);
        return;
    }

    // ---------------- uknn: blocks [520,784), 2 tasks each, gated on ballcnt ----------------
    for (int s = 0; s < 2; s++) {
        int u = (bid - 520) * 2 + s;
        int b = u / 66;
        int r = u - b * 66;
        int pi = (r < 7) ? 0 : (r < 17) ? 1 : (r < 30) ? 2 : (r < 46) ? 3 : 4;
        int xblk = r - c_npre[pi];
        int grp = pi * 8 + b;
        if (tid == 0) {
            while (aload(&flags[F_BALL + grp]) < NPOINT) __builtin_amdgcn_s_sleep(2);
        }
        __syncthreads();  // gates staging; also protects LDS reuse across s
        int ns = c_ns[pi];
        int M = NPOINT * ns;  // divisible by 8; xblk*128 < M by construction
        const float* pp = pred + (size_t)b * NN * 3;
        const int* gb = gidx + c_goff[pi] + (size_t)b * NPOINT * ns;
        float* fX = (float*)sm.uk.sX; float* fY = (float*)sm.uk.sY; float* fZ = (float*)sm.uk.sZ;
        for (int g2 = tid; g2 < M; g2 += 256) {
            int id = __hip_atomic_load(&gb[g2], __ATOMIC_RELAXED, __HIP_MEMORY_SCOPE_AGENT);
            fX[g2] = pp[id * 3 + 0]; fY[g2] = pp[id * 3 + 1]; fZ[g2] = pp[id * 3 + 2];
        }
        int rowA = xblk * 128 + lane;
        int rowB = rowA + 64;
        __syncthreads();
        float qAx = 0.f, qAy = 0.f, qAz = 0.f, qBx = 0.f, qBy = 0.f, qBz = 0.f;
        if (rowA < M) { qAx = fX[rowA]; qAy = fY[rowA]; qAz = fZ[rowA]; }
        if (rowB < M) { qBx = fX[rowB]; qBy = fY[rowB]; qBz = fZ[rowB]; }
        v2f qax = {qAx, qAx}, qay = {qAy, qAy}, qaz = {qAz, qAz};
        v2f qbx = {qBx, qBx}, qby = {qBy, qBy}, qbz = {qBz, qBz};
        v2f m1A = {1e30f, 1e30f}, m2A = {1e30f, 1e30f};
        v2f m1B = {1e30f, 1e30f}, m2B = {1e30f, 1e30f};
        int Mh = M >> 3;
        int j0 = wid * Mh;
#pragma unroll 4
        for (int jj = 0; jj < Mh; jj++) {
            v2f X = sm.uk.sX[j0 + jj], Y = sm.uk.sY[j0 + jj], Z = sm.uk.sZ[j0 + jj];
            // direct formula: exact 0 for bit-identical duplicates (padding!)
            v2f dxA = qax - X, dyA = qay - Y, dzA = qaz - Z;
            v2f dA = dxA * dxA + dyA * dyA + dzA * dzA;
            float l0 = fminf(m1A.x, dA.x), h0 = fmaxf(m1A.x, dA.x);
            float l1 = fminf(m1A.y, dA.y), h1 = fmaxf(m1A.y, dA.y);
            m1A = (v2f){l0, l1};
            m2A = (v2f){fminf(m2A.x, h0), fminf(m2A.y, h1)};
            v2f dxB = qbx - X, dyB = qby - Y, dzB = qbz - Z;
            v2f dB = dxB * dxB + dyB * dyB + dzB * dzB;
            float l2 = fminf(m1B.x, dB.x), h2 = fmaxf(m1B.x, dB.x);
            float l3 = fminf(m1B.y, dB.y), h3 = fmaxf(m1B.y, dB.y);
            m1B = (v2f){l2, l3};
            m2B = (v2f){fminf(m2B.x, h2), fminf(m2B.y, h3)};
        }
        // merge even/odd streams (exact: multiset (min1,min2) is order-independent)
        float a1 = fminf(m1A.x, m1A.y);
        float a2 = fminf(fmaxf(m1A.x, m1A.y), fminf(m2A.x, m2A.y));
        float b1 = fminf(m1B.x, m1B.y);
        float b2 = fminf(fmaxf(m1B.x, m1B.y), fminf(m2B.x, m2B.y));
        sm.uk.pm1[wid][lane] = a1; sm.uk.pm2[wid][lane] = a2;
        sm.uk.pm1[wid][64 + lane] = b1; sm.uk.pm2[wid][64 + lane] = b2;
        __syncthreads();
        if (tid < 128) {
            int row = xblk * 128 + tid;
            double v = 0.0;
            if (row < M) {
                float c1 = sm.uk.pm1[0][tid], c2 = sm.uk.pm2[0][tid];
#pragma unroll
                for (int w = 1; w < 4; w++) {
                    float d1 = sm.uk.pm1[w][tid], d2 = sm.uk.pm2[w][tid];
                    float n1 = fminf(c1, d1);
                    float n2 = fminf(fmaxf(c1, d1), fminf(c2, d2));
                    c1 = n1; c2 = n2;
                }
                v = (double)(sqrtf(c2) + 1e-8f);
            }
            for (int off = 32; off; off >>= 1) v += __shfl_down(v, off, 64);
            if ((tid & 63) == 0) astore_d(&part[OFF_UK + (grp * 20 + xblk) * 2 + (tid >> 6)], v);
        }
        __syncthreads();
    }
    __shared__ int lastFlag;
    if (tid == 0) {
        atomicAdd(&flags[F_DONE], 1);
        lastFlag = (atomicAdd(&flags[F_UKD], 1) == 263);
    }
    __syncthreads();
    if (!lastFlag) return;
    // last uknn block: wait for all 776 done-adds, then finalize
    if (tid == 0) {
        while (aload(&flags[F_DONE]) < DONE_TARGET) __builtin_amdgcn_s_sleep(2);
    }
    __syncthreads();
    if (tid < 64) {
        double s0 = 0.0, s1 = 0.0, sr = 0.0;
#pragma unroll
        for (int k = 0; k < 4; k++) {
            s0 += aload_d(&part[OFF_CD + lane + 64 * k]);
            s1 += aload_d(&part[OFF_CD + 256 + lane + 64 * k]);
            sr += aload_d(&part[OFF_REP + lane + 64 * k]);
        }
        double v = 0.0;
        if (lane < 40) {
            int pi2 = lane >> 3;
            int b2 = lane & 7;
            double m = 0.0;
            int base = OFF_UK + (pi2 * 8 + b2) * 40;
            int nsl = 2 * c_nblk[pi2];
            for (int k = 0; k < nsl; k++) m += aload_d(&part[base + k]);
            double p = c_p[pi2];
            int M2 = NPOINT * c_ns[pi2];
            double disk_area = M_PI * 1.0 / (double)NN;
            double e = sqrt(disk_area);
            m = m / (double)M2;
            double d = m - e;
            double w = (p * 100.0) * (p * 100.0);
            v = d * d / (e + 1e-8) * w / 40.0;  // /(8 batches * 5 percentages)
        }
        for (int off = 32; off; off >>= 1) {
            v += __shfl_down(v, off, 64);
            s0 += __shfl_down(s0, off, 64);
            s1 += __shfl_down(s1, off, 64);
            sr += __shfl_down(sr, off, 64);
        }
        if (lane == 0) {
            double cd = (0.8 * s0 + 0.2 * s1) / ((double)BB * NN) / (double)radius[0];
            double rep = sr / ((double)BB * NN * 4.0);
            out[0] = (float)(cd + rep + v);
        }
    }
}

extern "C" void kernel_launch(void* const* d_in, const int* in_sizes, int n_in,
                              void* d_out, int out_size, void* d_ws, size_t ws_size,
                              hipStream_t stream) {
    const float* pred = (const float*)d_in[0];
    const float* gt = (const float*)d_in[1];
    const float* radius = (const float*)d_in[2];
    float* out = (float*)d_out;

    double* part = (double*)d_ws;            // 2368 doubles of per-block partials
    int* flags = (int*)(part + 2368);        // 50 control ints (zeroed each call)
    int* fidx = flags + 64;                  // 8*102 ints
    int* gidx = fidx + BB * NPOINT;          // 65280 ints (all 5 pi regions)

    hipMemsetAsync(flags, 0, N_FLAGS * sizeof(int), stream);
    void* args_unused = nullptr; (void)args_unused;
    hipLaunchKernelGGL(k_mega, dim3(784), dim3(256), 0, stream,
                       pred, gt, radius, fidx, gidx, part, flags, out);
}

// Round 14
// 155.647 us; speedup vs baseline: 4.0529x; 4.0529x over previous
//
#include <hip/hip_runtime.h>
#include <math.h>

#define BB 8
#define NN 2048
#define NPOINT 102
#define H_REP 0.0005f
#define NBLK_UKNN (20 * 8 * 5)

typedef float v2f __attribute__((ext_vector_type(2)));

__device__ const int    c_ns[5]   = {8, 12, 16, 20, 24};
__device__ const double c_p[5]    = {0.004, 0.006, 0.008, 0.01, 0.012};
__device__ const int    c_goff[5] = {0, 6528, 16320, 29376, 45696};  // ints; 816*ns prefix

// part layout (doubles): cdpart[512] | reppart[256] | ukpart[1600]
#define OFF_CD 0
#define OFF_REP 512
#define OFF_UK 768
#define N_DBL 2368

__device__ inline double aload_d(const double* p) {
    return __hip_atomic_load(p, __ATOMIC_RELAXED, __HIP_MEMORY_SCOPE_AGENT);
}

// branchless sorted-5 insert (keeps t0<=t1<=t2<=t3<=t4)
__device__ inline void ins5(float c, float& t0, float& t1, float& t2, float& t3, float& t4) {
    float lo;
    lo = fminf(t0, c); c = fmaxf(t0, c); t0 = lo;
    lo = fminf(t1, c); c = fmaxf(t1, c); t1 = lo;
    lo = fminf(t2, c); c = fmaxf(t2, c); t2 = lo;
    lo = fminf(t3, c); c = fmaxf(t3, c); t3 = lo;
    t4 = fminf(t4, c);
}

union SMem {
    struct { float4 sB[NN]; float pm[4][128]; } cd;                      // 34 KB
    struct { float4 sP[NN]; float pm[4][64][5]; } rep;                   // 37.9 KB
    struct { float4 sP[NN]; float2 sl[2][4]; int sFi[NPOINT]; } fps;     // 32.5 KB
};

// ---------------- phase1: blocks [0,8)=fps  [8,264)=cd  [264,520)=rep ----------------
__global__ __launch_bounds__(256, 2) void k_phase1(const float* __restrict__ pred,
                                                   const float* __restrict__ gt,
                                                   int* __restrict__ fidx,
                                                   double* __restrict__ part,
                                                   int* __restrict__ done) {
    __shared__ SMem sm;
    int bid = blockIdx.x;
    int tid = threadIdx.x;
    int lane = tid & 63, wid = tid >> 6;

    if (bid == 8 && tid == 0) *done = 0;  // zero uknn completion counter (no memset needed)

    if (bid < 8) {
        // ========== FPS: 4 waves x 8 pts/lane, DPP argmax, fidx buffered in LDS ==========
        __builtin_amdgcn_s_setprio(1);
        int b = bid;
        const float* pp = pred + (size_t)b * NN * 3;
        float px[8], py[8], pz[8], dist[8];
#pragma unroll
        for (int k = 0; k < 8; k++) {
            int i = (wid << 9) + (k << 6) + lane;  // wave wid owns [wid*512, wid*512+512)
            float x = pp[i * 3 + 0], y = pp[i * 3 + 1], z = pp[i * 3 + 2];
            px[k] = x; py[k] = y; pz[k] = z; dist[k] = 1e10f;
            sm.fps.sP[i] = make_float4(x, y, z, 0.0f);
        }
        if (tid == 0) sm.fps.sFi[0] = 0;
        __syncthreads();
        int last = 0;
#pragma unroll 1
        for (int step = 1; step < NPOINT; ++step) {
            float4 lp = sm.fps.sP[last];
            float bv = -1.0f;
            int bi = 0;
#pragma unroll
            for (int k = 0; k < 8; k++) {
                float dx = px[k] - lp.x, dy = py[k] - lp.y, dz = pz[k] - lp.z;
                float nd = fminf(dist[k], dx * dx + dy * dy + dz * dz);
                dist[k] = nd;
                bool better = nd > bv;  // ascending k -> first-max kept (min global idx)
                bv = better ? nd : bv;
                bi = better ? ((wid << 9) + (k << 6) + lane) : bi;
            }
            // wave-64 argmax: row_ror 1,2,4,8 + bcast15/31 (idempotent -> bcast-safe)
            {
                float v2; int i2; bool take;
#define DPPC(CTRL)                                                                          \
                v2 = __int_as_float(__builtin_amdgcn_update_dpp(                            \
                        __float_as_int(bv), __float_as_int(bv), CTRL, 0xF, 0xF, false));    \
                i2 = __builtin_amdgcn_update_dpp(bi, bi, CTRL, 0xF, 0xF, false);            \
                take = (v2 > bv) || (v2 == bv && i2 < bi);                                  \
                bv = take ? v2 : bv; bi = take ? i2 : bi;
                DPPC(0x121)  // row_ror:1
                DPPC(0x122)  // row_ror:2
                DPPC(0x124)  // row_ror:4
                DPPC(0x128)  // row_ror:8
                DPPC(0x142)  // row_bcast15
                DPPC(0x143)  // row_bcast31
#undef DPPC
            }
            int pb = step & 1;
            if (lane == 63) sm.fps.sl[pb][wid] = make_float2(bv, __int_as_float(bi));
            __syncthreads();  // no pending vmem in loop -> lgkm-only drain
            float fv = -2.0f;
            int fi = 0;
#pragma unroll
            for (int w = 0; w < 4; w++) {  // ascending wave -> disjoint ascending idx ranges
                float2 s = sm.fps.sl[pb][w];
                int i2 = __float_as_int(s.y);
                bool take = (s.x > fv) || (s.x == fv && i2 < fi);
                fv = take ? s.x : fv;
                fi = take ? i2 : fi;
            }
            if (tid == 0) sm.fps.sFi[step] = fi;
            last = fi;  // uniform; double-buffered slots -> no second barrier
        }
        __syncthreads();
        for (int s = tid; s < NPOINT; s += 256) fidx[b * NPOINT + s] = sm.fps.sFi[s];
    } else if (bid < 264) {
        // ========== chamfer: 2 rows/lane (128 rows/block), 4 waves x 512-pt chunks ==========
        int r = bid - 8;
        int z = r >> 7;
        int b = (r >> 4) & 7;
        int xb = r & 15;
        const float* A = z ? pred : gt;
        const float* Bp = z ? gt : pred;
        const float* bb = Bp + (size_t)b * NN * 3;
        for (int j = tid; j < NN; j += 256) {
            sm.cd.sB[j] = make_float4(bb[j * 3 + 0], bb[j * 3 + 1], bb[j * 3 + 2], 0.0f);
        }
        int rowA = xb * 128 + lane;
        int rowB = rowA + 64;
        const float* aA = A + ((size_t)b * NN + rowA) * 3;
        const float* aB = A + ((size_t)b * NN + rowB) * 3;
        float axA = aA[0], ayA = aA[1], azA = aA[2];
        float axB = aB[0], ayB = aB[1], azB = aB[2];
        __syncthreads();
        float mnA = 1e30f, mnB = 1e30f;
        int j0 = wid * 512;
#pragma unroll 8
        for (int jj = 0; jj < 512; jj++) {
            float4 p = sm.cd.sB[j0 + jj];
            float dxA = axA - p.x, dyA = ayA - p.y, dzA = azA - p.z;
            mnA = fminf(mnA, dxA * dxA + dyA * dyA + dzA * dzA);
            float dxB = axB - p.x, dyB = ayB - p.y, dzB = azB - p.z;
            mnB = fminf(mnB, dxB * dxB + dyB * dyB + dzB * dzB);
        }
        sm.cd.pm[wid][lane] = mnA;
        sm.cd.pm[wid][64 + lane] = mnB;
        __syncthreads();
        if (tid < 128) {
            double v = (double)fminf(fminf(sm.cd.pm[0][tid], sm.cd.pm[1][tid]),
                                     fminf(sm.cd.pm[2][tid], sm.cd.pm[3][tid]));
            for (int off = 32; off; off >>= 1) v += __shfl_down(v, off, 64);
            if (lane == 0) part[OFF_CD + r * 2 + (tid >> 6)] = v;  // two slots/block
        }
    } else {
        // ========== repulsion: 4 waves x 512-pt chunks, 64 rows/block ==========
        int r = bid - 264;
        int b = r >> 5;
        int xb = r & 31;
        const float* pp = pred + (size_t)b * NN * 3;
        for (int j = tid; j < NN; j += 256) {
            sm.rep.sP[j] = make_float4(pp[j * 3 + 0], pp[j * 3 + 1], pp[j * 3 + 2], 0.0f);
        }
        int row = xb * 64 + lane;
        __syncthreads();
        float4 q = sm.rep.sP[row];
        float t0 = 1e30f, t1 = 1e30f, t2 = 1e30f, t3 = 1e30f, t4 = 1e30f;
        int j0 = wid * 512;
#pragma unroll 8
        for (int jj = 0; jj < 512; jj++) {
            float4 p = sm.rep.sP[j0 + jj];
            float dx = q.x - p.x, dy = q.y - p.y, dz = q.z - p.z;
            ins5(dx * dx + dy * dy + dz * dz, t0, t1, t2, t3, t4);
        }
        sm.rep.pm[wid][lane][0] = t0; sm.rep.pm[wid][lane][1] = t1;
        sm.rep.pm[wid][lane][2] = t2; sm.rep.pm[wid][lane][3] = t3;
        sm.rep.pm[wid][lane][4] = t4;
        __syncthreads();
        if (tid < 64) {
            t0 = sm.rep.pm[0][lane][0]; t1 = sm.rep.pm[0][lane][1]; t2 = sm.rep.pm[0][lane][2];
            t3 = sm.rep.pm[0][lane][3]; t4 = sm.rep.pm[0][lane][4];
#pragma unroll
            for (int w = 1; w < 4; w++) {
#pragma unroll
                for (int k = 0; k < 5; k++) ins5(sm.rep.pm[w][lane][k], t0, t1, t2, t3, t4);
            }
            float s = fmaxf(H_REP - t1, 0.f) + fmaxf(H_REP - t2, 0.f) +
                      fmaxf(H_REP - t3, 0.f) + fmaxf(H_REP - t4, 0.f);
            double v = (double)s;
            for (int off = 32; off; off >>= 1) v += __shfl_down(v, off, 64);
            if (tid == 0) part[OFF_REP + r] = v;
        }
    }
}

// ---------------- ball query, all 5 radii fused; 4 centers/block; writes cnt ----------
__global__ __launch_bounds__(256) void k_ball(const float* __restrict__ pcd,
                                              const int* __restrict__ fidx,
                                              int* __restrict__ gidx,
                                              int* __restrict__ cntbuf) {
    int pi = blockIdx.z;
    int b = blockIdx.y;
    int wid = threadIdx.x >> 6, lane = threadIdx.x & 63;
    int c = blockIdx.x * 4 + wid;
    if (c >= NPOINT) return;
    int ns = c_ns[pi];
    double rd = sqrt(c_p[pi]);
    float r2 = (float)(rd * rd);
    const float* pp = pcd + (size_t)b * NN * 3;
    int ci = fidx[b * NPOINT + c];
    float cx = pp[ci * 3 + 0], cy = pp[ci * 3 + 1], cz = pp[ci * 3 + 2];
    float sc = cx * cx + cy * cy + cz * cz;
    int* out = gidx + c_goff[pi] + ((size_t)b * NPOINT + c) * ns;
    int cnt = 0;
    int first = 0;
    for (int j0 = 0; j0 < NN && cnt < ns; j0 += 64) {
        int j = j0 + lane;
        float x = pp[j * 3 + 0], y = pp[j * 3 + 1], z = pp[j * 3 + 2];
        float sj = x * x + y * y + z * z;
        float d2 = fmaxf(sc + sj - 2.0f * (cx * x + cy * y + cz * z), 0.0f);
        bool pred2 = d2 < r2;
        unsigned long long mask = __ballot(pred2);
        if (cnt == 0 && mask != 0ull) first = j0 + (int)__builtin_ctzll(mask);
        if (pred2) {
            int pos = cnt + (int)__popcll(mask & ((1ull << lane) - 1ull));
            if (pos < ns) out[pos] = j;
        }
        cnt += (int)__popcll(mask);
    }
    if (cnt < ns) {
        for (int s = cnt + lane; s < ns; s += 64) out[s] = first;
    }
    if (lane == 0) cntbuf[(pi * 8 + b) * NPOINT + c] = min(cnt, ns);
}

// ---------------- kNN-2 compacted: only selected rows queried; pads weighted --------
// Exactness: a padded row duplicates its center's first-selected point; identical
// points see the identical candidate multiset, so pad value == first-row value.
// Sum over group = sum_selected w*value with w(first)=1+(ns-cnt), w(other)=1.
__global__ __launch_bounds__(256, 4) void k_uknn(const float* __restrict__ pcd,
                                                 const int* __restrict__ gidx,
                                                 const int* __restrict__ cntbuf,
                                                 double* __restrict__ part,
                                                 int* __restrict__ done,
                                                 const float* __restrict__ radius,
                                                 float* __restrict__ out) {
    __shared__ v2f sX[1224], sY[1224], sZ[1224];  // SoA pairs, ~29.4 KB
    __shared__ float pm1[4][128], pm2[4][128];    // 4 KB
    __shared__ int scnt[NPOINT];
    __shared__ int spre[NPOINT + 1];
    __shared__ int lastFlag;
    int pi = blockIdx.z;
    int b = blockIdx.y;
    int grp = pi * 8 + b;
    int ns = c_ns[pi];
    int M = NPOINT * ns;
    int tid = threadIdx.x;
    int lane = tid & 63, wid = tid >> 6;
    // stage counts + exclusive prefix (Hillis-Steele, 103 entries)
    if (tid < NPOINT) scnt[tid] = cntbuf[grp * NPOINT + tid];
    __syncthreads();
    if (tid <= NPOINT) spre[tid] = (tid >= 1) ? scnt[tid - 1] : 0;
    __syncthreads();
    for (int s = 1; s <= NPOINT; s <<= 1) {
        int t = 0;
        if (tid <= NPOINT && tid >= s) t = spre[tid - s];
        __syncthreads();
        if (tid <= NPOINT) spre[tid] += t;
        __syncthreads();
    }
    int Q = spre[NPOINT];
    int slotbase = blockIdx.x * 128;
    int myslot = OFF_UK + (grp * 20 + blockIdx.x) * 2;
    bool active = (slotbase < Q);
    if (active) {
        const float* pp = pcd + (size_t)b * NN * 3;
        const int* gb = gidx + c_goff[pi] + (size_t)b * NPOINT * ns;
        float* fX = (float*)sX; float* fY = (float*)sY; float* fZ = (float*)sZ;
        for (int g = tid; g < M; g += 256) {
            int id = gb[g];
            fX[g] = pp[id * 3 + 0]; fY[g] = pp[id * 3 + 1]; fZ[g] = pp[id * 3 + 2];
        }
        __syncthreads();
        // resolve the two query slots handled by this lane
        float qx[2] = {0.f, 0.f}, qy[2] = {0.f, 0.f}, qz[2] = {0.f, 0.f};
#pragma unroll
        for (int h = 0; h < 2; h++) {
            int q = slotbase + lane + 64 * h;
            if (q < Q) {
                int lo = 0, hi = NPOINT - 1;
#pragma unroll
                for (int it = 0; it < 7; ++it) {  // 2^7 = 128 > 102
                    int mid = (lo + hi + 1) >> 1;
                    bool ge = (spre[mid] <= q);
                    lo = ge ? mid : lo;
                    hi = ge ? hi : mid - 1;
                }
                int g = lo * ns + (q - spre[lo]);
                qx[h] = fX[g]; qy[h] = fY[g]; qz[h] = fZ[g];
            }
        }
        v2f qax = {qx[0], qx[0]}, qay = {qy[0], qy[0]}, qaz = {qz[0], qz[0]};
        v2f qbx = {qx[1], qx[1]}, qby = {qy[1], qy[1]}, qbz = {qz[1], qz[1]};
        v2f m1A = {1e30f, 1e30f}, m2A = {1e30f, 1e30f};
        v2f m1B = {1e30f, 1e30f}, m2B = {1e30f, 1e30f};
        int Mh = M >> 3;  // v2f candidate pairs per wave chunk
        int j0 = wid * Mh;
#pragma unroll 4
        for (int jj = 0; jj < Mh; jj++) {
            v2f X = sX[j0 + jj], Y = sY[j0 + jj], Z = sZ[j0 + jj];
            // direct formula: exact 0 for bit-identical duplicates (padding!)
            v2f dxA = qax - X, dyA = qay - Y, dzA = qaz - Z;
            v2f dA = dxA * dxA + dyA * dyA + dzA * dzA;  // v_pk_mul/fma_f32
            float l0 = fminf(m1A.x, dA.x), h0 = fmaxf(m1A.x, dA.x);
            float l1 = fminf(m1A.y, dA.y), h1 = fmaxf(m1A.y, dA.y);
            m1A = (v2f){l0, l1};
            m2A = (v2f){fminf(m2A.x, h0), fminf(m2A.y, h1)};
            v2f dxB = qbx - X, dyB = qby - Y, dzB = qbz - Z;
            v2f dB = dxB * dxB + dyB * dyB + dzB * dzB;
            float l2 = fminf(m1B.x, dB.x), h2 = fmaxf(m1B.x, dB.x);
            float l3 = fminf(m1B.y, dB.y), h3 = fmaxf(m1B.y, dB.y);
            m1B = (v2f){l2, l3};
            m2B = (v2f){fminf(m2B.x, h2), fminf(m2B.y, h3)};
        }
        // merge even/odd streams (exact: multiset (min1,min2) is order-independent)
        float a1 = fminf(m1A.x, m1A.y);
        float a2 = fminf(fmaxf(m1A.x, m1A.y), fminf(m2A.x, m2A.y));
        float b1 = fminf(m1B.x, m1B.y);
        float b2 = fminf(fmaxf(m1B.x, m1B.y), fminf(m2B.x, m2B.y));
        pm1[wid][lane] = a1; pm2[wid][lane] = a2;
        pm1[wid][64 + lane] = b1; pm2[wid][64 + lane] = b2;
        __syncthreads();
        if (tid < 128) {
            int q = slotbase + tid;
            double v = 0.0;
            if (q < Q) {
                float c1 = pm1[0][tid], c2 = pm2[0][tid];
#pragma unroll
                for (int w = 1; w < 4; w++) {
                    float d1 = pm1[w][tid], d2 = pm2[w][tid];
                    float n1 = fminf(c1, d1);
                    float n2 = fminf(fmaxf(c1, d1), fminf(c2, d2));
                    c1 = n1; c2 = n2;
                }
                // weight: first-selected row of a center carries its pad duplicates
                int lo = 0, hi = NPOINT - 1;
#pragma unroll
                for (int it = 0; it < 7; ++it) {
                    int mid = (lo + hi + 1) >> 1;
                    bool ge = (spre[mid] <= q);
                    lo = ge ? mid : lo;
                    hi = ge ? hi : mid - 1;
                }
                int pos = q - spre[lo];
                double w = (pos == 0) ? (double)(1 + ns - scnt[lo]) : 1.0;
                v = w * (double)(sqrtf(c2) + 1e-8f);
            }
            for (int off = 32; off; off >>= 1) v += __shfl_down(v, off, 64);
            if ((tid & 63) == 0) part[myslot + (tid >> 6)] = v;
        }
    } else if (tid == 0) {
        part[myslot + 0] = 0.0;
        part[myslot + 1] = 0.0;
    }
    // -------- last-block-done: fused finalize --------
    __threadfence();
    __syncthreads();
    if (tid == 0) lastFlag = (atomicAdd(done, 1) == NBLK_UKNN - 1);
    __syncthreads();
    if (!lastFlag) return;
    __threadfence();
    if (tid >= 64) return;
    double s0 = 0.0, s1 = 0.0, sr = 0.0;
#pragma unroll
    for (int k = 0; k < 4; k++) {
        s0 += aload_d(&part[OFF_CD + lane + 64 * k]);
        s1 += aload_d(&part[OFF_CD + 256 + lane + 64 * k]);
        sr += aload_d(&part[OFF_REP + lane + 64 * k]);
    }
    double v = 0.0;
    if (lane < 40) {
        int pi2 = lane >> 3;
        int b2 = lane & 7;
        double m = 0.0;
        int base = OFF_UK + (pi2 * 8 + b2) * 40;
        for (int k = 0; k < 40; k++) m += aload_d(&part[base + k]);
        double p = c_p[pi2];
        int M2 = NPOINT * c_ns[pi2];
        double disk_area = M_PI * 1.0 / (double)NN;
        double e = sqrt(disk_area);
        m = m / (double)M2;
        double d = m - e;
        double w = (p * 100.0) * (p * 100.0);
        v = d * d / (e + 1e-8) * w / 40.0;  // /(8 batches * 5 percentages)
    }
    for (int off = 32; off; off >>= 1) {
        v += __shfl_down(v, off, 64);
        s0 += __shfl_down(s0, off, 64);
        s1 += __shfl_down(s1, off, 64);
        sr += __shfl_down(sr, off, 64);
    }
    if (lane == 0) {
        double cd = (0.8 * s0 + 0.2 * s1) / ((double)BB * NN) / (double)radius[0];
        double rep = sr / ((double)BB * NN * 4.0);
        out[0] = (float)(cd + rep + v);
    }
}

extern "C" void kernel_launch(void* const* d_in, const int* in_sizes, int n_in,
                              void* d_out, int out_size, void* d_ws, size_t ws_size,
                              hipStream_t stream) {
    const float* pred = (const float*)d_in[0];
    const float* gt = (const float*)d_in[1];
    const float* radius = (const float*)d_in[2];
    float* out = (float*)d_out;

    double* part = (double*)d_ws;            // 2368 doubles of per-block partials
    int* ints = (int*)(part + N_DBL);
    int* done = ints;                        // zeroed by phase1 block 8
    int* fidx = ints + 16;                   // 8*102
    int* cntbuf = fidx + BB * NPOINT;        // 40*102
    int* gidx = cntbuf + 40 * NPOINT;        // 65280 (all 5 pi regions)

    hipLaunchKernelGGL(k_phase1, dim3(520), dim3(256), 0, stream, pred, gt, fidx, part, done);
    hipLaunchKernelGGL(k_ball, dim3(26, BB, 5), dim3(256), 0, stream, pred, fidx, gidx, cntbuf);
    hipLaunchKernelGGL(k_uknn, dim3(20, BB, 5), dim3(256), 0, stream, pred, gidx, cntbuf,
                       part, done, radius, out);
}

// Round 15
// 145.938 us; speedup vs baseline: 4.3225x; 1.0665x over previous
//
#include <hip/hip_runtime.h>
#include <math.h>

#define BB 8
#define NN 2048
#define NPOINT 102
#define H_REP 0.0005f

typedef float v2f __attribute__((ext_vector_type(2)));

__device__ const int    c_ns[5] = {8, 12, 16, 20, 24};
__device__ const double c_p[5]  = {0.004, 0.006, 0.008, 0.01, 0.012};

// part layout (doubles): cdpart[512] | reppart[256] | ukpart[80]
#define OFF_CD 0
#define OFF_REP 512
#define OFF_UK 768
#define N_DBL 896

__device__ inline double aload_d(const double* p) {
    return __hip_atomic_load(p, __ATOMIC_RELAXED, __HIP_MEMORY_SCOPE_AGENT);
}

// branchless sorted-5 insert (keeps t0<=t1<=t2<=t3<=t4)
__device__ inline void ins5(float c, float& t0, float& t1, float& t2, float& t3, float& t4) {
    float lo;
    lo = fminf(t0, c); c = fmaxf(t0, c); t0 = lo;
    lo = fminf(t1, c); c = fmaxf(t1, c); t1 = lo;
    lo = fminf(t2, c); c = fmaxf(t2, c); t2 = lo;
    lo = fminf(t3, c); c = fmaxf(t3, c); t3 = lo;
    t4 = fminf(t4, c);
}

union SMemP1 {
    struct { float4 sB[NN]; float pm[2][4][128]; } cd;       // 32K + 4K
    struct { float4 sP[NN]; float pm[2][4][64][5]; } rep;    // 32K + 10K
    struct {                                                 // ~50.1K
        float sx[2][NN], sy[2][NN], sz[2][NN];
        float2 sl[2][2][4];
        int sFi[2][NPOINT];
    } fps;
};

// ---------------- phase1: blocks [0,4)=fps(2 batches each)  [4,132)=cd  [132,260)=rep --
__global__ __launch_bounds__(512, 4) void k_phase1(const float* __restrict__ pred,
                                                   const float* __restrict__ gt,
                                                   int* __restrict__ fidx,
                                                   double* __restrict__ part,
                                                   int* __restrict__ done) {
    __shared__ SMemP1 sm;
    int bid = blockIdx.x;
    int tid = threadIdx.x;
    int lane = tid & 63, wid = tid >> 6;

    if (bid == 4 && tid == 0) *done = 0;  // zero tail completion counter

    if (bid < 4) {
        // ===== FPS: 2 batches/block, 4 waves each (r7 per-batch structure verbatim).
        //       SIMD s hosts wave s (batch A) + wave s+4 (batch B): 2 chains/SIMD
        //       so each chain's latency hides under the other's issue. =====
        __builtin_amdgcn_s_setprio(1);
        int h = wid >> 2;   // batch half within block
        int s = wid & 3;    // sub-wave within batch
        int b = bid * 2 + h;
        const float* pp = pred + (size_t)b * NN * 3;
        float px[8], py[8], pz[8], dist[8];
#pragma unroll
        for (int k = 0; k < 8; k++) {
            int i = (s << 9) + (k << 6) + lane;  // sub-wave owns [s*512, s*512+512)
            float x = pp[i * 3 + 0], y = pp[i * 3 + 1], z = pp[i * 3 + 2];
            px[k] = x; py[k] = y; pz[k] = z; dist[k] = 1e10f;
            sm.fps.sx[h][i] = x; sm.fps.sy[h][i] = y; sm.fps.sz[h][i] = z;
        }
        if ((tid & 255) == 0) sm.fps.sFi[h][0] = 0;
        __syncthreads();
        int last = 0;
#pragma unroll 1
        for (int step = 1; step < NPOINT; ++step) {
            float lx = sm.fps.sx[h][last], ly = sm.fps.sy[h][last], lz = sm.fps.sz[h][last];
            float bv = -1.0f;
            int bi = 0;
#pragma unroll
            for (int k = 0; k < 8; k++) {
                float dx = px[k] - lx, dy = py[k] - ly, dz = pz[k] - lz;
                float nd = fminf(dist[k], dx * dx + dy * dy + dz * dz);
                dist[k] = nd;
                bool better = nd > bv;  // ascending k -> first-max kept (min global idx)
                bv = better ? nd : bv;
                bi = better ? ((s << 9) + (k << 6) + lane) : bi;
            }
            // wave-64 argmax: row_ror 1,2,4,8 + bcast15/31 (idempotent -> bcast-safe)
            {
                float v2; int i2; bool take;
#define DPPC(CTRL)                                                                          \
                v2 = __int_as_float(__builtin_amdgcn_update_dpp(                            \
                        __float_as_int(bv), __float_as_int(bv), CTRL, 0xF, 0xF, false));    \
                i2 = __builtin_amdgcn_update_dpp(bi, bi, CTRL, 0xF, 0xF, false);            \
                take = (v2 > bv) || (v2 == bv && i2 < bi);                                  \
                bv = take ? v2 : bv; bi = take ? i2 : bi;
                DPPC(0x121)
                DPPC(0x122)
                DPPC(0x124)
                DPPC(0x128)
                DPPC(0x142)
                DPPC(0x143)
#undef DPPC
            }
            int pb = step & 1;
            if (lane == 63) sm.fps.sl[pb][h][s] = make_float2(bv, __int_as_float(bi));
            __syncthreads();  // block-wide; both batches in lockstep
            float fv = -2.0f;
            int fi = 0;
#pragma unroll
            for (int w = 0; w < 4; w++) {  // own batch's 4 slots, ascending idx ranges
                float2 sv = sm.fps.sl[pb][h][w];
                int i2 = __float_as_int(sv.y);
                bool take = (sv.x > fv) || (sv.x == fv && i2 < fi);
                fv = take ? sv.x : fv;
                fi = take ? i2 : fi;
            }
            if ((tid & 255) == 0) sm.fps.sFi[h][step] = fi;
            last = fi;  // uniform per half; double-buffered slots -> 1 barrier/step
        }
        __syncthreads();
        for (int t = tid; t < 2 * NPOINT; t += 512) {
            int hh = (t >= NPOINT);
            int st = t - hh * NPOINT;
            fidx[(bid * 2 + hh) * NPOINT + st] = sm.fps.sFi[hh][st];
        }
    } else if (bid < 132) {
        // ===== chamfer: 256 rows/block (two old blocks sharing one staged tile) =====
        int r = bid - 4;          // [0,128)
        int z = r >> 6;
        int b = (r >> 3) & 7;
        int xb = r & 7;           // 8 x-blocks of 256 rows
        const float* A = z ? pred : gt;
        const float* Bp = z ? gt : pred;
        const float* bb = Bp + (size_t)b * NN * 3;
        for (int j = tid; j < NN; j += 512) {
            sm.cd.sB[j] = make_float4(bb[j * 3 + 0], bb[j * 3 + 1], bb[j * 3 + 2], 0.0f);
        }
        int h = wid >> 2, sw = wid & 3;
        int rowA = xb * 256 + h * 128 + lane;
        int rowB = rowA + 64;
        const float* aA = A + ((size_t)b * NN + rowA) * 3;
        const float* aB = A + ((size_t)b * NN + rowB) * 3;
        float axA = aA[0], ayA = aA[1], azA = aA[2];
        float axB = aB[0], ayB = aB[1], azB = aB[2];
        __syncthreads();
        float mnA = 1e30f, mnB = 1e30f;
        int j0 = sw * 512;
#pragma unroll 8
        for (int jj = 0; jj < 512; jj++) {
            float4 p = sm.cd.sB[j0 + jj];
            float dxA = axA - p.x, dyA = ayA - p.y, dzA = azA - p.z;
            mnA = fminf(mnA, dxA * dxA + dyA * dyA + dzA * dzA);
            float dxB = axB - p.x, dyB = ayB - p.y, dzB = azB - p.z;
            mnB = fminf(mnB, dxB * dxB + dyB * dyB + dzB * dzB);
        }
        sm.cd.pm[h][sw][lane] = mnA;
        sm.cd.pm[h][sw][64 + lane] = mnB;
        __syncthreads();
        if (tid < 256) {
            int hh = tid >> 7, idx = tid & 127;
            double v = (double)fminf(
                fminf(sm.cd.pm[hh][0][idx], sm.cd.pm[hh][1][idx]),
                fminf(sm.cd.pm[hh][2][idx], sm.cd.pm[hh][3][idx]));
            for (int off = 32; off; off >>= 1) v += __shfl_down(v, off, 64);
            if ((tid & 63) == 0) part[OFF_CD + r * 4 + (tid >> 6)] = v;
        }
    } else {
        // ===== repulsion: 128 rows/block (two old blocks sharing one staged tile) =====
        int r = bid - 132;        // [0,128)
        int b = r >> 4;
        int xb = r & 15;          // 16 x-blocks of 128 rows
        const float* pp = pred + (size_t)b * NN * 3;
        for (int j = tid; j < NN; j += 512) {
            sm.rep.sP[j] = make_float4(pp[j * 3 + 0], pp[j * 3 + 1], pp[j * 3 + 2], 0.0f);
        }
        int h = wid >> 2, sw = wid & 3;
        int row = xb * 128 + h * 64 + lane;
        __syncthreads();
        float4 q = sm.rep.sP[row];
        float t0 = 1e30f, t1 = 1e30f, t2 = 1e30f, t3 = 1e30f, t4 = 1e30f;
        int j0 = sw * 512;
#pragma unroll 8
        for (int jj = 0; jj < 512; jj++) {
            float4 p = sm.rep.sP[j0 + jj];
            float dx = q.x - p.x, dy = q.y - p.y, dz = q.z - p.z;
            ins5(dx * dx + dy * dy + dz * dz, t0, t1, t2, t3, t4);
        }
        sm.rep.pm[h][sw][lane][0] = t0; sm.rep.pm[h][sw][lane][1] = t1;
        sm.rep.pm[h][sw][lane][2] = t2; sm.rep.pm[h][sw][lane][3] = t3;
        sm.rep.pm[h][sw][lane][4] = t4;
        __syncthreads();
        if (tid < 128) {
            int hh = tid >> 6, l2 = tid & 63;
            t0 = sm.rep.pm[hh][0][l2][0]; t1 = sm.rep.pm[hh][0][l2][1];
            t2 = sm.rep.pm[hh][0][l2][2]; t3 = sm.rep.pm[hh][0][l2][3];
            t4 = sm.rep.pm[hh][0][l2][4];
#pragma unroll
            for (int w = 1; w < 4; w++) {
#pragma unroll
                for (int k = 0; k < 5; k++) ins5(sm.rep.pm[hh][w][l2][k], t0, t1, t2, t3, t4);
            }
            float sv = fmaxf(H_REP - t1, 0.f) + fmaxf(H_REP - t2, 0.f) +
                       fmaxf(H_REP - t3, 0.f) + fmaxf(H_REP - t4, 0.f);
            double v = (double)sv;
            for (int off = 32; off; off >>= 1) v += __shfl_down(v, off, 64);
            if ((tid & 63) == 0) part[OFF_REP + r * 2 + hh] = v;
        }
    }
}

// ---------------- tail: 1 block per (pi,b) group: ball -> scan -> compressed kNN-2 ----
// Compression exactness: a pad duplicates its center's first-selected point, so the
// candidate multiset = selected points with multiplicity (first gets 1+ns-cnt). For
// (min1,min2) a multiplicity cap of 2 is sufficient -> stage first twice when cnt<ns.
// Query rows = selected slots only, weighted w(first)=1+ns-cnt, w(other)=1.
__global__ __launch_bounds__(1024, 4) void k_tail(const float* __restrict__ pred,
                                                  const int* __restrict__ fidx,
                                                  double* __restrict__ part,
                                                  int* __restrict__ done,
                                                  const float* __restrict__ radius,
                                                  float* __restrict__ out) {
    __shared__ int gidxL[2448];                   // 9.8 KB (selected idx, per-center stride ns)
    __shared__ v2f sX[1280], sY[1280], sZ[1280];  // 30.7 KB compressed candidates (max 2560)
    __shared__ float pm1[16][128], pm2[16][128];  // 16 KB
    __shared__ int scnt[NPOINT];
    __shared__ int spre[NPOINT + 1];              // packed prefix: low16=queries, high16=cands
    __shared__ int lastFlag;
    int grp = blockIdx.x;                         // pi*8 + b
    int pi = grp >> 3, b = grp & 7;
    int ns = c_ns[pi];
    int tid = threadIdx.x, lane = tid & 63, wid = tid >> 6;
    const float* pp = pred + (size_t)b * NN * 3;
    double rd = sqrt(c_p[pi]);
    float r2 = (float)(rd * rd);

    // ---- ball: 102 center-tasks over 16 waves ----
    for (int c = wid; c < NPOINT; c += 16) {
        int ci = fidx[b * NPOINT + c];
        float cx = pp[ci * 3 + 0], cy = pp[ci * 3 + 1], cz = pp[ci * 3 + 2];
        float sc = cx * cx + cy * cy + cz * cz;
        int cnt = 0;
        for (int j0 = 0; j0 < NN && cnt < ns; j0 += 64) {
            int j = j0 + lane;
            float x = pp[j * 3 + 0], y = pp[j * 3 + 1], z = pp[j * 3 + 2];
            float sj = x * x + y * y + z * z;
            float d2 = fmaxf(sc + sj - 2.0f * (cx * x + cy * y + cz * z), 0.0f);
            bool prd = d2 < r2;
            unsigned long long mask = __ballot(prd);
            if (prd) {
                int pos = cnt + (int)__popcll(mask & ((1ull << lane) - 1ull));
                if (pos < ns) gidxL[c * ns + pos] = j;
            }
            cnt += (int)__popcll(mask);
        }
        if (lane == 0) scnt[c] = min(cnt, ns);    // cnt>=1 always (center is in cloud)
    }
    __syncthreads();
    // ---- packed exclusive prefix scan over 103 entries ----
    if (tid <= NPOINT) {
        int v = 0;
        if (tid >= 1) {
            int sc_ = scnt[tid - 1];
            v = sc_ | ((sc_ + (sc_ < ns ? 1 : 0)) << 16);
        }
        spre[tid] = v;
    }
    __syncthreads();
    for (int s = 1; s <= NPOINT; s <<= 1) {
        int t = 0;
        if (tid <= NPOINT && tid >= s) t = spre[tid - s];
        __syncthreads();
        if (tid <= NPOINT) spre[tid] += t;
        __syncthreads();
    }
    int Q = spre[NPOINT] & 0xffff;
    int CC = spre[NPOINT] >> 16;
    int CCpad = (CC + 255) & ~255;                // <= 2560
    // ---- stage compressed candidates ----
    float* fX = (float*)sX; float* fY = (float*)sY; float* fZ = (float*)sZ;
    for (int s = tid; s < CCpad; s += 1024) {
        float x = 1e30f, y = 1e30f, z = 1e30f;
        if (s < CC) {
            int lo = 0, hi = NPOINT - 1;
#pragma unroll
            for (int it = 0; it < 7; ++it) {
                int mid = (lo + hi + 1) >> 1;
                bool ge = ((spre[mid] >> 16) <= s);
                lo = ge ? mid : lo;
                hi = ge ? hi : mid - 1;
            }
            int p = s - (spre[lo] >> 16);
            int dup = (scnt[lo] < ns) ? 1 : 0;
            int id = gidxL[lo * ns + max(0, p - dup)];
            x = pp[id * 3 + 0]; y = pp[id * 3 + 1]; z = pp[id * 3 + 2];
        }
        fX[s] = x; fY[s] = y; fZ[s] = z;
    }
    __syncthreads();
    // ---- weighted compacted queries: tiles of 128, waves split candidates ----
    int CHp = CCpad >> 5;                          // v2f pairs per wave
    int j0p = wid * CHp;
    double racc = 0.0;
    for (int tb = 0; tb < Q; tb += 128) {
        float qx[2], qy[2], qz[2];
        double wgt[2];
#pragma unroll
        for (int hh = 0; hh < 2; hh++) {
            int q = tb + lane + 64 * hh;
            qx[hh] = 0.f; qy[hh] = 0.f; qz[hh] = 0.f; wgt[hh] = 0.0;
            if (q < Q) {
                int lo = 0, hi = NPOINT - 1;
#pragma unroll
                for (int it = 0; it < 7; ++it) {
                    int mid = (lo + hi + 1) >> 1;
                    bool ge = ((spre[mid] & 0xffff) <= q);
                    lo = ge ? mid : lo;
                    hi = ge ? hi : mid - 1;
                }
                int p = q - (spre[lo] & 0xffff);
                int dup = (scnt[lo] < ns) ? 1 : 0;
                int cslot = (spre[lo] >> 16) + (p == 0 ? 0 : p + dup);
                qx[hh] = fX[cslot]; qy[hh] = fY[cslot]; qz[hh] = fZ[cslot];
                wgt[hh] = (p == 0) ? (double)(1 + ns - scnt[lo]) : 1.0;
            }
        }
        v2f qax = {qx[0], qx[0]}, qay = {qy[0], qy[0]}, qaz = {qz[0], qz[0]};
        v2f qbx = {qx[1], qx[1]}, qby = {qy[1], qy[1]}, qbz = {qz[1], qz[1]};
        v2f m1A = {1e30f, 1e30f}, m2A = {1e30f, 1e30f};
        v2f m1B = {1e30f, 1e30f}, m2B = {1e30f, 1e30f};
#pragma unroll 4
        for (int jj = 0; jj < CHp; jj++) {
            v2f X = sX[j0p + jj], Y = sY[j0p + jj], Z = sZ[j0p + jj];
            // direct formula: exact 0 for bit-identical duplicates
            v2f dxA = qax - X, dyA = qay - Y, dzA = qaz - Z;
            v2f dA = dxA * dxA + dyA * dyA + dzA * dzA;
            float l0 = fminf(m1A.x, dA.x), h0 = fmaxf(m1A.x, dA.x);
            float l1 = fminf(m1A.y, dA.y), h1 = fmaxf(m1A.y, dA.y);
            m1A = (v2f){l0, l1};
            m2A = (v2f){fminf(m2A.x, h0), fminf(m2A.y, h1)};
            v2f dxB = qbx - X, dyB = qby - Y, dzB = qbz - Z;
            v2f dB = dxB * dxB + dyB * dyB + dzB * dzB;
            float l2 = fminf(m1B.x, dB.x), h2 = fmaxf(m1B.x, dB.x);
            float l3 = fminf(m1B.y, dB.y), h3 = fmaxf(m1B.y, dB.y);
            m1B = (v2f){l2, l3};
            m2B = (v2f){fminf(m2B.x, h2), fminf(m2B.y, h3)};
        }
        // merge even/odd streams (multiset (min1,min2) is order-independent -> exact)
        float a1 = fminf(m1A.x, m1A.y);
        float a2 = fminf(fmaxf(m1A.x, m1A.y), fminf(m2A.x, m2A.y));
        float b1 = fminf(m1B.x, m1B.y);
        float b2 = fminf(fmaxf(m1B.x, m1B.y), fminf(m2B.x, m2B.y));
        pm1[wid][lane] = a1; pm2[wid][lane] = a2;
        pm1[wid][64 + lane] = b1; pm2[wid][64 + lane] = b2;
        __syncthreads();
        if (tid < 128) {
            float c1 = pm1[0][tid], c2 = pm2[0][tid];
#pragma unroll
            for (int w = 1; w < 16; w++) {
                float d1 = pm1[w][tid], d2 = pm2[w][tid];
                float n1 = fminf(c1, d1);
                float n2 = fminf(fmaxf(c1, d1), fminf(c2, d2));
                c1 = n1; c2 = n2;
            }
            int q = tb + tid;
            double v = 0.0;
            if (q < Q) v = wgt[tid >> 6] * (double)(sqrtf(c2) + 1e-8f);
            for (int off = 32; off; off >>= 1) v += __shfl_down(v, off, 64);
            if ((tid & 63) == 0) racc += v;
        }
        __syncthreads();  // pm reuse next tile
    }
    if (tid == 0) part[OFF_UK + grp * 2 + 0] = racc;
    if (tid == 64) part[OFF_UK + grp * 2 + 1] = racc;
    // -------- last-block-done: fused finalize --------
    __threadfence();
    __syncthreads();
    if (tid == 0) lastFlag = (atomicAdd(done, 1) == 39);
    __syncthreads();
    if (!lastFlag) return;
    __threadfence();
    if (tid >= 64) return;
    double s0 = 0.0, s1 = 0.0, sr = 0.0;
#pragma unroll
    for (int k = 0; k < 4; k++) {
        s0 += aload_d(&part[OFF_CD + lane + 64 * k]);
        s1 += aload_d(&part[OFF_CD + 256 + lane + 64 * k]);
        sr += aload_d(&part[OFF_REP + lane + 64 * k]);
    }
    double v = 0.0;
    if (lane < 40) {
        int pi2 = lane >> 3;
        double m = aload_d(&part[OFF_UK + lane * 2]) + aload_d(&part[OFF_UK + lane * 2 + 1]);
        double p = c_p[pi2];
        int M2 = NPOINT * c_ns[pi2];
        double disk_area = M_PI * 1.0 / (double)NN;
        double e = sqrt(disk_area);
        m = m / (double)M2;
        double d = m - e;
        double w = (p * 100.0) * (p * 100.0);
        v = d * d / (e + 1e-8) * w / 40.0;  // /(8 batches * 5 percentages)
    }
    for (int off = 32; off; off >>= 1) {
        v += __shfl_down(v, off, 64);
        s0 += __shfl_down(s0, off, 64);
        s1 += __shfl_down(s1, off, 64);
        sr += __shfl_down(sr, off, 64);
    }
    if (lane == 0) {
        double cd = (0.8 * s0 + 0.2 * s1) / ((double)BB * NN) / (double)radius[0];
        double rep = sr / ((double)BB * NN * 4.0);
        out[0] = (float)(cd + rep + v);
    }
}

extern "C" void kernel_launch(void* const* d_in, const int* in_sizes, int n_in,
                              void* d_out, int out_size, void* d_ws, size_t ws_size,
                              hipStream_t stream) {
    const float* pred = (const float*)d_in[0];
    const float* gt = (const float*)d_in[1];
    const float* radius = (const float*)d_in[2];
    float* out = (float*)d_out;

    double* part = (double*)d_ws;            // 896 doubles of per-block partials
    int* ints = (int*)(part + N_DBL);
    int* done = ints;                        // zeroed by phase1 block 4
    int* fidx = ints + 16;                   // 8*102

    hipLaunchKernelGGL(k_phase1, dim3(260), dim3(512), 0, stream, pred, gt, fidx, part, done);
    hipLaunchKernelGGL(k_tail, dim3(40), dim3(1024), 0, stream, pred, fidx, part, done,
                       radius, out);
}

// Round 16
// 138.649 us; speedup vs baseline: 4.5498x; 1.0526x over previous
//
#include <hip/hip_runtime.h>
#include <math.h>

#define BB 8
#define NN 2048
#define NPOINT 102
#define H_REP 0.0005f

typedef float v2f __attribute__((ext_vector_type(2)));

__device__ const int    c_ns[5] = {8, 12, 16, 20, 24};
__device__ const double c_p[5]  = {0.004, 0.006, 0.008, 0.01, 0.012};

// part layout (doubles): cdpart[512] | reppart[256] | ukpart[80]
#define OFF_CD 0
#define OFF_REP 512
#define OFF_UK 768
#define N_DBL 896

__device__ inline double aload_d(const double* p) {
    return __hip_atomic_load(p, __ATOMIC_RELAXED, __HIP_MEMORY_SCOPE_AGENT);
}

// branchless sorted-5 insert (keeps t0<=t1<=t2<=t3<=t4)
__device__ inline void ins5(float c, float& t0, float& t1, float& t2, float& t3, float& t4) {
    float lo;
    lo = fminf(t0, c); c = fmaxf(t0, c); t0 = lo;
    lo = fminf(t1, c); c = fmaxf(t1, c); t1 = lo;
    lo = fminf(t2, c); c = fmaxf(t2, c); t2 = lo;
    lo = fminf(t3, c); c = fmaxf(t3, c); t3 = lo;
    t4 = fminf(t4, c);
}

union SMemP1 {
    struct { float4 sB[NN]; float pm[4][128]; } cd;        // 34 KB
    struct { float4 sP[NN]; float pm[4][64][5]; } rep;     // 37.9 KB
    struct { float4 sl4[2][4]; float slz[2][4]; int sFi[NPOINT]; } fps;  // tiny
};

// ---------------- phase1: blocks [0,8)=fps  [8,264)=cd  [264,520)=rep ----------------
__global__ __launch_bounds__(256, 2) void k_phase1(const float* __restrict__ pred,
                                                   const float* __restrict__ gt,
                                                   int* __restrict__ fidx,
                                                   double* __restrict__ part,
                                                   int* __restrict__ done) {
    __shared__ SMemP1 sm;
    int bid = blockIdx.x;
    int tid = threadIdx.x;
    int lane = tid & 63, wid = tid >> 6;

    if (bid == 8 && tid == 0) *done = 0;  // zero tail completion counter

    if (bid < 8) {
        // ========== FPS: 4 waves x 8 pts/lane, (value,idx) DPP argmax; winner COORDS
        //   carried via the LDS slot (owner lane self-identifies post-DPP) -> no
        //   dependent sP[last] read on the critical path, no 32KB point buffer. ==========
        __builtin_amdgcn_s_setprio(1);
        int b = bid;
        const float* pp = pred + (size_t)b * NN * 3;
        float px[8], py[8], pz[8], dist[8];
#pragma unroll
        for (int k = 0; k < 8; k++) {
            int i = (wid << 9) + (k << 6) + lane;  // wave wid owns [wid*512, wid*512+512)
            px[k] = pp[i * 3 + 0];
            py[k] = pp[i * 3 + 1];
            pz[k] = pp[i * 3 + 2];
            dist[k] = 1e10f;
        }
        if (tid == 0) sm.fps.sFi[0] = 0;
        float lx = pp[0], ly = pp[1], lz = pp[2];  // point 0 (uniform scalar loads)
#pragma unroll 1
        for (int step = 1; step < NPOINT; ++step) {
            float bv = -1.0f;  // nd >= 0 > -1 -> k=0 always taken first
            int bi = 0;
#pragma unroll
            for (int k = 0; k < 8; k++) {
                float dx = px[k] - lx, dy = py[k] - ly, dz = pz[k] - lz;
                float nd = fminf(dist[k], dx * dx + dy * dy + dz * dz);
                dist[k] = nd;
                bool better = nd > bv;  // ascending k -> first-max kept (min global idx)
                bv = better ? nd : bv;
                bi = better ? ((wid << 9) + (k << 6) + lane) : bi;
            }
            // wave-64 (value,idx) argmax: row_ror 1,2,4,8 + bcast15/31 (idempotent)
            {
                float v2; int i2; bool take;
#define DPPC(CTRL)                                                                          \
                v2 = __int_as_float(__builtin_amdgcn_update_dpp(                            \
                        __float_as_int(bv), __float_as_int(bv), CTRL, 0xF, 0xF, false));    \
                i2 = __builtin_amdgcn_update_dpp(bi, bi, CTRL, 0xF, 0xF, false);            \
                take = (v2 > bv) || (v2 == bv && i2 < bi);                                  \
                bv = take ? v2 : bv; bi = take ? i2 : bi;
                DPPC(0x121)  // row_ror:1
                DPPC(0x122)  // row_ror:2
                DPPC(0x124)  // row_ror:4
                DPPC(0x128)  // row_ror:8
                DPPC(0x142)  // row_bcast15
                DPPC(0x143)  // row_bcast31
#undef DPPC
            }
            // owner lane (the one holding winner bi) writes slot WITH coords
            float wx = 0.f, wy = 0.f, wz = 0.f;
            bool own = false;
#pragma unroll
            for (int k = 0; k < 8; k++) {
                bool m = (bi == ((wid << 9) + (k << 6) + lane));
                wx = m ? px[k] : wx;
                wy = m ? py[k] : wy;
                wz = m ? pz[k] : wz;
                own = own || m;
            }
            int pb = step & 1;
            if (own) {
                sm.fps.sl4[pb][wid] = make_float4(bv, __int_as_float(bi), wx, wy);
                sm.fps.slz[pb][wid] = wz;
            }
            __syncthreads();  // no pending vmem in loop -> lgkm-only drain
            // all threads redundantly merge the 4 wave winners (broadcast LDS reads)
            float fv = -2.0f, fx = 0.f, fy = 0.f, fz = 0.f;
            int fi = 0;
#pragma unroll
            for (int w = 0; w < 4; w++) {  // ascending wave -> disjoint ascending idx ranges
                float4 s4 = sm.fps.sl4[pb][w];
                float szv = sm.fps.slz[pb][w];
                int i2 = __float_as_int(s4.y);
                bool take = (s4.x > fv) || (s4.x == fv && i2 < fi);
                fv = take ? s4.x : fv; fi = take ? i2 : fi;
                fx = take ? s4.z : fx; fy = take ? s4.w : fy;
                fz = take ? szv : fz;
            }
            if (tid == 0) sm.fps.sFi[step] = fi;
            lx = fx; ly = fy; lz = fz;  // next query point straight from merge
        }
        __syncthreads();
        for (int s = tid; s < NPOINT; s += 256) fidx[b * NPOINT + s] = sm.fps.sFi[s];
    } else if (bid < 264) {
        // ========== chamfer: 2 rows/lane (128 rows/block), 4 waves x 512-pt chunks ==========
        int r = bid - 8;
        int z = r >> 7;
        int b = (r >> 4) & 7;
        int xb = r & 15;
        const float* A = z ? pred : gt;
        const float* Bp = z ? gt : pred;
        const float* bb = Bp + (size_t)b * NN * 3;
        for (int j = tid; j < NN; j += 256) {
            sm.cd.sB[j] = make_float4(bb[j * 3 + 0], bb[j * 3 + 1], bb[j * 3 + 2], 0.0f);
        }
        int rowA = xb * 128 + lane;
        int rowB = rowA + 64;
        const float* aA = A + ((size_t)b * NN + rowA) * 3;
        const float* aB = A + ((size_t)b * NN + rowB) * 3;
        float axA = aA[0], ayA = aA[1], azA = aA[2];
        float axB = aB[0], ayB = aB[1], azB = aB[2];
        __syncthreads();
        float mnA = 1e30f, mnB = 1e30f;
        int j0 = wid * 512;
#pragma unroll 8
        for (int jj = 0; jj < 512; jj++) {
            float4 p = sm.cd.sB[j0 + jj];
            float dxA = axA - p.x, dyA = ayA - p.y, dzA = azA - p.z;
            mnA = fminf(mnA, dxA * dxA + dyA * dyA + dzA * dzA);
            float dxB = axB - p.x, dyB = ayB - p.y, dzB = azB - p.z;
            mnB = fminf(mnB, dxB * dxB + dyB * dyB + dzB * dzB);
        }
        sm.cd.pm[wid][lane] = mnA;
        sm.cd.pm[wid][64 + lane] = mnB;
        __syncthreads();
        if (tid < 128) {
            double v = (double)fminf(fminf(sm.cd.pm[0][tid], sm.cd.pm[1][tid]),
                                     fminf(sm.cd.pm[2][tid], sm.cd.pm[3][tid]));
            for (int off = 32; off; off >>= 1) v += __shfl_down(v, off, 64);
            if (lane == 0) part[OFF_CD + r * 2 + (tid >> 6)] = v;  // two slots/block
        }
    } else {
        // ========== repulsion: 4 waves x 512-pt chunks, 64 rows/block ==========
        int r = bid - 264;
        int b = r >> 5;
        int xb = r & 31;
        const float* pp = pred + (size_t)b * NN * 3;
        for (int j = tid; j < NN; j += 256) {
            sm.rep.sP[j] = make_float4(pp[j * 3 + 0], pp[j * 3 + 1], pp[j * 3 + 2], 0.0f);
        }
        int row = xb * 64 + lane;
        __syncthreads();
        float4 q = sm.rep.sP[row];
        float t0 = 1e30f, t1 = 1e30f, t2 = 1e30f, t3 = 1e30f, t4 = 1e30f;
        int j0 = wid * 512;
#pragma unroll 8
        for (int jj = 0; jj < 512; jj++) {
            float4 p = sm.rep.sP[j0 + jj];
            float dx = q.x - p.x, dy = q.y - p.y, dz = q.z - p.z;
            ins5(dx * dx + dy * dy + dz * dz, t0, t1, t2, t3, t4);
        }
        sm.rep.pm[wid][lane][0] = t0; sm.rep.pm[wid][lane][1] = t1;
        sm.rep.pm[wid][lane][2] = t2; sm.rep.pm[wid][lane][3] = t3;
        sm.rep.pm[wid][lane][4] = t4;
        __syncthreads();
        if (tid < 64) {
            t0 = sm.rep.pm[0][lane][0]; t1 = sm.rep.pm[0][lane][1]; t2 = sm.rep.pm[0][lane][2];
            t3 = sm.rep.pm[0][lane][3]; t4 = sm.rep.pm[0][lane][4];
#pragma unroll
            for (int w = 1; w < 4; w++) {
#pragma unroll
                for (int k = 0; k < 5; k++) ins5(sm.rep.pm[w][lane][k], t0, t1, t2, t3, t4);
            }
            float s = fmaxf(H_REP - t1, 0.f) + fmaxf(H_REP - t2, 0.f) +
                      fmaxf(H_REP - t3, 0.f) + fmaxf(H_REP - t4, 0.f);
            double v = (double)s;
            for (int off = 32; off; off >>= 1) v += __shfl_down(v, off, 64);
            if (tid == 0) part[OFF_REP + r] = v;
        }
    }
}

// ---------------- tail: 1 block/(pi,b): LDS-staged ball -> scan -> compressed kNN-2 ----
// Compression exactness: pads duplicate the first-selected point; multiplicity cap 2
// preserves (min1,min2); query first-row weight = 1+ns-cnt. (absmax=0 validated r15.)
union UTail {
    struct { float sx[NN], sy[NN], sz[NN]; } st;        // 24.6 KB (ball + cand staging)
    struct { float pm1[16][128], pm2[16][128]; } pm;    // 16 KB  (query merge)
};

__global__ __launch_bounds__(1024, 1) void k_tail(const float* __restrict__ pred,
                                                  const int* __restrict__ fidx,
                                                  double* __restrict__ part,
                                                  int* __restrict__ done,
                                                  const float* __restrict__ radius,
                                                  float* __restrict__ out) {
    __shared__ UTail ut;
    __shared__ unsigned short gidxL[2448];        // 4.9 KB (selected idx, stride ns)
    __shared__ v2f cX[1232], cY[1232], cZ[1232];  // 29.6 KB compressed candidates (<=2464)
    __shared__ int scnt[NPOINT];
    __shared__ int spre[NPOINT + 1];              // packed prefix: low16=queries, high16=cands
    __shared__ int lastFlag;
    int grp = blockIdx.x;                         // pi*8 + b
    int pi = grp >> 3, b = grp & 7;
    int ns = c_ns[pi];
    int tid = threadIdx.x, lane = tid & 63, wid = tid >> 6;
    const float* pp = pred + (size_t)b * NN * 3;
    double rd = sqrt(c_p[pi]);
    float r2 = (float)(rd * rd);

    // ---- stage cloud into LDS (coalesced global reads, scattered LDS writes) ----
    for (int t = tid; t < 3 * NN; t += 1024) {
        float v = pp[t];
        int idx = t / 3;
        int comp = t - idx * 3;
        if (comp == 0) ut.st.sx[idx] = v;
        else if (comp == 1) ut.st.sy[idx] = v;
        else ut.st.sz[idx] = v;
    }
    __syncthreads();

    // ---- ball: 102 center-tasks over 16 waves; full scan (no data-dependent exit,
    //      identical result: writes capped at pos<ns), unrolled -> pipelined ds_reads ----
    for (int c = wid; c < NPOINT; c += 16) {
        int ci = fidx[b * NPOINT + c];
        float cx = ut.st.sx[ci], cy = ut.st.sy[ci], cz = ut.st.sz[ci];
        float sc = cx * cx + cy * cy + cz * cz;
        int cnt = 0;
#pragma unroll 4
        for (int j0 = 0; j0 < NN; j0 += 64) {
            int j = j0 + lane;
            float x = ut.st.sx[j], y = ut.st.sy[j], z = ut.st.sz[j];
            float sj = x * x + y * y + z * z;
            float d2 = fmaxf(sc + sj - 2.0f * (cx * x + cy * y + cz * z), 0.0f);
            bool prd = d2 < r2;
            unsigned long long mask = __ballot(prd);
            if (prd) {
                int pos = cnt + (int)__popcll(mask & ((1ull << lane) - 1ull));
                if (pos < ns) gidxL[c * ns + pos] = (unsigned short)j;
            }
            cnt += (int)__popcll(mask);
        }
        if (lane == 0) scnt[c] = min(cnt, ns);  // cnt>=1 (center is in the cloud)
    }
    __syncthreads();
    // ---- packed exclusive prefix scan over 103 entries ----
    if (tid <= NPOINT) {
        int v = 0;
        if (tid >= 1) {
            int sc_ = scnt[tid - 1];
            v = sc_ | ((sc_ + (sc_ < ns ? 1 : 0)) << 16);
        }
        spre[tid] = v;
    }
    __syncthreads();
    for (int s = 1; s <= NPOINT; s <<= 1) {
        int t = 0;
        if (tid <= NPOINT && tid >= s) t = spre[tid - s];
        __syncthreads();
        if (tid <= NPOINT) spre[tid] += t;
        __syncthreads();
    }
    int Q = spre[NPOINT] & 0xffff;
    int CC = spre[NPOINT] >> 16;
    int CCpad = (CC + 31) & ~31;                  // <= 2464
    // ---- stage compressed candidates (reads ut.st -> writes cX/cY/cZ) ----
    float* fX = (float*)cX; float* fY = (float*)cY; float* fZ = (float*)cZ;
    for (int s = tid; s < CCpad; s += 1024) {
        float x = 1e30f, y = 1e30f, z = 1e30f;
        if (s < CC) {
            int lo = 0, hi = NPOINT - 1;
#pragma unroll
            for (int it = 0; it < 7; ++it) {
                int mid = (lo + hi + 1) >> 1;
                bool ge = ((spre[mid] >> 16) <= s);
                lo = ge ? mid : lo;
                hi = ge ? hi : mid - 1;
            }
            int p = s - (spre[lo] >> 16);
            int dup = (scnt[lo] < ns) ? 1 : 0;
            int id = gidxL[lo * ns + max(0, p - dup)];
            x = ut.st.sx[id]; y = ut.st.sy[id]; z = ut.st.sz[id];
        }
        fX[s] = x; fY[s] = y; fZ[s] = z;
    }
    __syncthreads();  // ut.st dead from here; ut.pm live (union)
    // ---- weighted compacted queries: tiles of 128, waves split candidates ----
    int CHp = CCpad >> 5;                          // v2f pairs per wave
    int j0p = wid * CHp;
    double racc = 0.0;
    for (int tb = 0; tb < Q; tb += 128) {
        float qx[2], qy[2], qz[2];
        double wgt[2];
#pragma unroll
        for (int hh = 0; hh < 2; hh++) {
            int q = tb + lane + 64 * hh;
            qx[hh] = 0.f; qy[hh] = 0.f; qz[hh] = 0.f; wgt[hh] = 0.0;
            if (q < Q) {
                int lo = 0, hi = NPOINT - 1;
#pragma unroll
                for (int it = 0; it < 7; ++it) {
                    int mid = (lo + hi + 1) >> 1;
                    bool ge = ((spre[mid] & 0xffff) <= q);
                    lo = ge ? mid : lo;
                    hi = ge ? hi : mid - 1;
                }
                int p = q - (spre[lo] & 0xffff);
                int dup = (scnt[lo] < ns) ? 1 : 0;
                int cslot = (spre[lo] >> 16) + (p == 0 ? 0 : p + dup);
                qx[hh] = fX[cslot]; qy[hh] = fY[cslot]; qz[hh] = fZ[cslot];
                wgt[hh] = (p == 0) ? (double)(1 + ns - scnt[lo]) : 1.0;
            }
        }
        v2f qax = {qx[0], qx[0]}, qay = {qy[0], qy[0]}, qaz = {qz[0], qz[0]};
        v2f qbx = {qx[1], qx[1]}, qby = {qy[1], qy[1]}, qbz = {qz[1], qz[1]};
        v2f m1A = {1e30f, 1e30f}, m2A = {1e30f, 1e30f};
        v2f m1B = {1e30f, 1e30f}, m2B = {1e30f, 1e30f};
#pragma unroll 4
        for (int jj = 0; jj < CHp; jj++) {
            v2f X = cX[j0p + jj], Y = cY[j0p + jj], Z = cZ[j0p + jj];
            // direct formula: exact 0 for bit-identical duplicates
            v2f dxA = qax - X, dyA = qay - Y, dzA = qaz - Z;
            v2f dA = dxA * dxA + dyA * dyA + dzA * dzA;
            float l0 = fminf(m1A.x, dA.x), h0 = fmaxf(m1A.x, dA.x);
            float l1 = fminf(m1A.y, dA.y), h1 = fmaxf(m1A.y, dA.y);
            m1A = (v2f){l0, l1};
            m2A = (v2f){fminf(m2A.x, h0), fminf(m2A.y, h1)};
            v2f dxB = qbx - X, dyB = qby - Y, dzB = qbz - Z;
            v2f dB = dxB * dxB + dyB * dyB + dzB * dzB;
            float l2 = fminf(m1B.x, dB.x), h2 = fmaxf(m1B.x, dB.x);
            float l3 = fminf(m1B.y, dB.y), h3 = fmaxf(m1B.y, dB.y);
            m1B = (v2f){l2, l3};
            m2B = (v2f){fminf(m2B.x, h2), fminf(m2B.y, h3)};
        }
        // merge even/odd streams (multiset (min1,min2) is order-independent -> exact)
        float a1 = fminf(m1A.x, m1A.y);
        float a2 = fminf(fmaxf(m1A.x, m1A.y), fminf(m2A.x, m2A.y));
        float b1 = fminf(m1B.x, m1B.y);
        float b2 = fminf(fmaxf(m1B.x, m1B.y), fminf(m2B.x, m2B.y));
        ut.pm.pm1[wid][lane] = a1; ut.pm.pm2[wid][lane] = a2;
        ut.pm.pm1[wid][64 + lane] = b1; ut.pm.pm2[wid][64 + lane] = b2;
        __syncthreads();
        if (tid < 128) {
            float c1 = ut.pm.pm1[0][tid], c2 = ut.pm.pm2[0][tid];
#pragma unroll
            for (int w = 1; w < 16; w++) {
                float d1 = ut.pm.pm1[w][tid], d2 = ut.pm.pm2[w][tid];
                float n1 = fminf(c1, d1);
                float n2 = fminf(fmaxf(c1, d1), fminf(c2, d2));
                c1 = n1; c2 = n2;
            }
            int q = tb + tid;
            double v = 0.0;
            if (q < Q) v = wgt[tid >> 6] * (double)(sqrtf(c2) + 1e-8f);
            for (int off = 32; off; off >>= 1) v += __shfl_down(v, off, 64);
            if ((tid & 63) == 0) racc += v;
        }
        __syncthreads();  // pm reuse next tile
    }
    if (tid == 0) part[OFF_UK + grp * 2 + 0] = racc;
    if (tid == 64) part[OFF_UK + grp * 2 + 1] = racc;
    // -------- last-block-done: fused finalize --------
    __threadfence();
    __syncthreads();
    if (tid == 0) lastFlag = (atomicAdd(done, 1) == 39);
    __syncthreads();
    if (!lastFlag) return;
    __threadfence();
    if (tid >= 64) return;
    double s0 = 0.0, s1 = 0.0, sr = 0.0;
#pragma unroll
    for (int k = 0; k < 4; k++) {
        s0 += aload_d(&part[OFF_CD + lane + 64 * k]);
        s1 += aload_d(&part[OFF_CD + 256 + lane + 64 * k]);
        sr += aload_d(&part[OFF_REP + lane + 64 * k]);
    }
    double v = 0.0;
    if (lane < 40) {
        int pi2 = lane >> 3;
        double m = aload_d(&part[OFF_UK + lane * 2]) + aload_d(&part[OFF_UK + lane * 2 + 1]);
        double p = c_p[pi2];
        int M2 = NPOINT * c_ns[pi2];
        double disk_area = M_PI * 1.0 / (double)NN;
        double e = sqrt(disk_area);
        m = m / (double)M2;
        double d = m - e;
        double w = (p * 100.0) * (p * 100.0);
        v = d * d / (e + 1e-8) * w / 40.0;  // /(8 batches * 5 percentages)
    }
    for (int off = 32; off; off >>= 1) {
        v += __shfl_down(v, off, 64);
        s0 += __shfl_down(s0, off, 64);
        s1 += __shfl_down(s1, off, 64);
        sr += __shfl_down(sr, off, 64);
    }
    if (lane == 0) {
        double cd = (0.8 * s0 + 0.2 * s1) / ((double)BB * NN) / (double)radius[0];
        double rep = sr / ((double)BB * NN * 4.0);
        out[0] = (float)(cd + rep + v);
    }
}

extern "C" void kernel_launch(void* const* d_in, const int* in_sizes, int n_in,
                              void* d_out, int out_size, void* d_ws, size_t ws_size,
                              hipStream_t stream) {
    const float* pred = (const float*)d_in[0];
    const float* gt = (const float*)d_in[1];
    const float* radius = (const float*)d_in[2];
    float* out = (float*)d_out;

    double* part = (double*)d_ws;            // 896 doubles of per-block partials
    int* ints = (int*)(part + N_DBL);
    int* done = ints;                        // zeroed by phase1 block 8
    int* fidx = ints + 16;                   // 8*102

    hipLaunchKernelGGL(k_phase1, dim3(520), dim3(256), 0, stream, pred, gt, fidx, part, done);
    hipLaunchKernelGGL(k_tail, dim3(40), dim3(1024), 0, stream, pred, fidx, part, done,
                       radius, out);
}